// Round 2
// baseline (763.086 us; speedup 1.0000x reference)
//
#include <hip/hip_runtime.h>
#include <math.h>

// Problem constants (fixed by the reference)
#define BATCH 16
#define SMAX 4096
#define DMODEL 4096
#define NH 32
#define NKV 8
#define NREP 4
#define DH 128
#define QKCOLS 5120   // 4096 (q) + 1024 (k)
#define NCHUNK 8      // s-dimension split for flash-decode
#define CHUNK 512     // positions per chunk
#define TILE 64       // positions per LDS tile
#define NDCH 32       // d-chunks for gemv
#define DCH 128       // d per chunk
#define RECS 132      // attn partial record stride (floats; 132*4B = 16B-aligned)

// ---------------------------------------------------------------------------
// Transpose x[b][d] -> xt[d][b] so gemv can read x via SGPR (scalar) loads.
// ---------------------------------------------------------------------------
__global__ __launch_bounds__(256) void transpose_x(
    const float* __restrict__ x, float* __restrict__ xt)
{
    int g = blockIdx.x * 256 + threadIdx.x;   // 65536 = 16*4096
    int b = g >> 12, d = g & 4095;
    xt[d * BATCH + b] = x[g];
}

// ---------------------------------------------------------------------------
// GEMV partials: part[ch][b][col] = sum_{d in chunk} xt[d][b] * w[d][col]
// x read via wave-uniform (scalar) loads -> zero LDS/DS usage; w coalesced.
// grid: (totC/256, NDCH), block 256
// ---------------------------------------------------------------------------
__global__ __launch_bounds__(256) void gemv_part(
    const float* __restrict__ xt,   // [4096][16]
    const float* __restrict__ w1, int c1,
    const float* __restrict__ w2, int c2,
    float* __restrict__ part)       // [NDCH][16][c1+c2]
{
    const int col = blockIdx.x * 256 + threadIdx.x;
    const int ch = blockIdx.y;
    const int totC = c1 + c2;
    const int d0 = ch * DCH;

    const float* w; int stride, wcol;
    if (col < c1) { w = w1; stride = c1; wcol = col; }
    else          { w = w2; stride = c2; wcol = col - c1; }

    const float* wp = w + (size_t)d0 * stride + wcol;
    const float* xp = xt + d0 * BATCH;   // wave-uniform base

    float acc[BATCH];
#pragma unroll
    for (int b = 0; b < BATCH; ++b) acc[b] = 0.f;

    for (int d = 0; d < DCH; d += 4) {
        float wa = wp[(size_t)(d + 0) * stride];
        float wb = wp[(size_t)(d + 1) * stride];
        float wc = wp[(size_t)(d + 2) * stride];
        float wd = wp[(size_t)(d + 3) * stride];
#pragma unroll
        for (int b = 0; b < BATCH; ++b) {
            float a = acc[b];
            a = fmaf(xp[(d + 0) * BATCH + b], wa, a);   // uniform -> s_load
            a = fmaf(xp[(d + 1) * BATCH + b], wb, a);
            a = fmaf(xp[(d + 2) * BATCH + b], wc, a);
            a = fmaf(xp[(d + 3) * BATCH + b], wd, a);
            acc[b] = a;
        }
    }
#pragma unroll
    for (int b = 0; b < BATCH; ++b)
        part[((size_t)ch * BATCH + b) * totC + col] = acc[b];
}

// ---------------------------------------------------------------------------
// Reduce NDCH partials + apply RoPE (interleaved even/odd pairs).
// ---------------------------------------------------------------------------
__global__ __launch_bounds__(256) void rope_reduce(
    const float* __restrict__ part,  // [NDCH][16][5120]
    const float* __restrict__ fcos, const float* __restrict__ fsin,
    float* __restrict__ xqk)         // [16][5120]
{
    int g = blockIdx.x * 256 + threadIdx.x;      // pair id: 16*2560
    int b = g / 2560;
    int po = g % 2560;
    float e = 0.f, o = 0.f;
    const float* p = part + (size_t)b * QKCOLS + 2 * po;
#pragma unroll
    for (int ch = 0; ch < NDCH; ++ch) {
        float2 v = *(const float2*)(p + (size_t)ch * BATCH * QKCOLS);
        e += v.x; o += v.y;
    }
    int i = po & 63;                 // pair index within a head (DH/2 = 64)
    float c = fcos[i], s = fsin[i];
    xqk[(size_t)b * QKCOLS + 2 * po]     = e * c - o * s;
    xqk[(size_t)b * QKCOLS + 2 * po + 1] = e * s + o * c;
}

// ---------------------------------------------------------------------------
// Flash-decode attention partial (V == K). grid (8 chunks, 8 kv, 16 b),
// block 256 = 4 waves. Scores: lane=row, wave=rep (q via scalar loads, no
// butterflies). PV: all 4 reps per k-read (tile read once). K tile is
// XOR-swizzled in LDS so both row-mode and contiguous b128 are conflict-free.
// ---------------------------------------------------------------------------
__global__ __launch_bounds__(256) void attn_part_kernel(
    const float* __restrict__ cache_k,  // [16][4096][8][128]
    const float* __restrict__ xqk,      // [16][5120]
    const int* __restrict__ sp,
    float* __restrict__ outp)           // [b][kv][chunk][rep][RECS]
{
    const int chunk = blockIdx.x;
    const int kv = blockIdx.y;
    const int b = blockIdx.z;
    const int t = threadIdx.x;
    const int lane = t & 63;
    const int w = t >> 6;               // wave id == rep (score phase)
    const int start_pos = sp[0];

    __shared__ __align__(16) float k_lds[TILE * DH];    // 32 KB, swizzled
    __shared__ __align__(16) float p_lds[TILE * NREP];  // [j][rep], 1 KB
    __shared__ __align__(16) float alpha_lds[NREP];

    const float* qw = xqk + (size_t)b * QKCOLS + (kv * NREP + w) * DH; // wave-uniform
    const float* xknew = xqk + (size_t)b * QKCOLS + DMODEL + kv * DH;
    const float* kbase = cache_k + ((size_t)b * SMAX * NKV + kv) * DH;
    const float scale = 0.08838834764831845f;  // 1/sqrt(128)

    const int jhalf = lane >> 5, cqo = lane & 31;   // PV mapping
    float m_run = -1e30f, l_run = 0.f;
    float4 acc[NREP];
#pragma unroll
    for (int r = 0; r < NREP; ++r) acc[r] = make_float4(0.f, 0.f, 0.f, 0.f);

    // prefetch tile 0 into registers
    float4 pf[8];
    {
        int s_base = chunk * CHUNK;
#pragma unroll
        for (int it = 0; it < 8; ++it) {
            int f = it * 256 + t, row = f >> 5, cq = f & 31;
            int s = s_base + row;
            const float* src = (s == start_pos) ? (xknew + 4 * cq)
                             : (kbase + (size_t)s * (NKV * DH) + 4 * cq);
            pf[it] = *(const float4*)src;
        }
    }

    for (int tt = 0; tt < CHUNK / TILE; ++tt) {
        const int s_base = chunk * CHUNK + tt * TILE;
        __syncthreads();   // prior tile's PV / p_lds reads complete
#pragma unroll
        for (int it = 0; it < 8; ++it) {
            int f = it * 256 + t, row = f >> 5, cq = f & 31;
            *(float4*)&k_lds[row * DH + 4 * (cq ^ (row & 7))] = pf[it];
        }
        __syncthreads();
        // prefetch next tile (overlaps with compute below)
        if (tt + 1 < CHUNK / TILE) {
            int nb = s_base + TILE;
#pragma unroll
            for (int it = 0; it < 8; ++it) {
                int f = it * 256 + t, row = f >> 5, cq = f & 31;
                int s = nb + row;
                const float* src = (s == start_pos) ? (xknew + 4 * cq)
                                 : (kbase + (size_t)s * (NKV * DH) + 4 * cq);
                pf[it] = *(const float4*)src;
            }
        }

        // ---- scores: lane=row full 128-dot; q operands from SGPRs ----
        float sc = 0.f;
#pragma unroll
        for (int cq = 0; cq < 32; ++cq) {
            const float4 k4 = *(const float4*)&k_lds[lane * DH + 4 * (cq ^ (lane & 7))];
            sc += qw[4 * cq + 0] * k4.x + qw[4 * cq + 1] * k4.y
                + qw[4 * cq + 2] * k4.z + qw[4 * cq + 3] * k4.w;
        }
        sc *= scale;
        const bool valid = (s_base + lane) <= start_pos;
        sc = valid ? sc : -1e30f;

        // ---- wave-private online softmax (rep == wave) ----
        float m_tile = sc;
#pragma unroll
        for (int m = 1; m < 64; m <<= 1)
            m_tile = fmaxf(m_tile, __shfl_xor(m_tile, m, 64));
        float m_new = fmaxf(m_run, m_tile);
        float alpha = __expf(m_run - m_new);
        float p = valid ? __expf(sc - m_new) : 0.f;
        float ps = p;
#pragma unroll
        for (int m = 1; m < 64; m <<= 1)
            ps += __shfl_xor(ps, m, 64);
        l_run = l_run * alpha + ps;
        m_run = m_new;
        p_lds[lane * NREP + w] = p;
        if (lane == 0) alpha_lds[w] = alpha;
        __syncthreads();

        // ---- rescale + PV (all 4 reps per k-read; tile read once) ----
        const float4 a4 = *(const float4*)alpha_lds;
        float al[NREP] = { a4.x, a4.y, a4.z, a4.w };
#pragma unroll
        for (int r = 0; r < NREP; ++r) {
            acc[r].x *= al[r]; acc[r].y *= al[r];
            acc[r].z *= al[r]; acc[r].w *= al[r];
        }
#pragma unroll
        for (int jj = 0; jj < 8; ++jj) {
            const int j = 16 * w + 8 * jhalf + jj;       // j&7 == jj
            const float4 p4 = *(const float4*)&p_lds[j * NREP];
            const float4 k4 = *(const float4*)&k_lds[j * DH + 4 * (cqo ^ jj)];
            acc[0].x = fmaf(p4.x, k4.x, acc[0].x);
            acc[0].y = fmaf(p4.x, k4.y, acc[0].y);
            acc[0].z = fmaf(p4.x, k4.z, acc[0].z);
            acc[0].w = fmaf(p4.x, k4.w, acc[0].w);
            acc[1].x = fmaf(p4.y, k4.x, acc[1].x);
            acc[1].y = fmaf(p4.y, k4.y, acc[1].y);
            acc[1].z = fmaf(p4.y, k4.z, acc[1].z);
            acc[1].w = fmaf(p4.y, k4.w, acc[1].w);
            acc[2].x = fmaf(p4.z, k4.x, acc[2].x);
            acc[2].y = fmaf(p4.z, k4.y, acc[2].y);
            acc[2].z = fmaf(p4.z, k4.z, acc[2].z);
            acc[2].w = fmaf(p4.z, k4.w, acc[2].w);
            acc[3].x = fmaf(p4.w, k4.x, acc[3].x);
            acc[3].y = fmaf(p4.w, k4.y, acc[3].y);
            acc[3].z = fmaf(p4.w, k4.z, acc[3].z);
            acc[3].w = fmaf(p4.w, k4.w, acc[3].w);
        }
    }

    // ---- combine the 8 (wave, jhalf) partial accs per (rep, col-quad) ----
    __syncthreads();                       // k_lds tile data no longer needed
    float* dst = &k_lds[t * 16];
    *(float4*)(dst + 0)  = acc[0];
    *(float4*)(dst + 4)  = acc[1];
    *(float4*)(dst + 8)  = acc[2];
    *(float4*)(dst + 12) = acc[3];
    __syncthreads();
    if (t < 128) {
        const int cq2 = t & 31, rep = t >> 5;
        float4 sum = make_float4(0.f, 0.f, 0.f, 0.f);
#pragma unroll
        for (int src = 0; src < 8; ++src) {
            int tsrc = (src >> 1) * 64 + (src & 1) * 32 + cq2;
            const float4 v = *(const float4*)&k_lds[tsrc * 16 + rep * 4];
            sum.x += v.x; sum.y += v.y; sum.z += v.z; sum.w += v.w;
        }
        float* rec = outp + ((((size_t)b * NKV + kv) * NCHUNK + chunk) * NREP + rep) * RECS;
        *(float4*)&rec[4 * cq2] = sum;
    }
    if (lane == 0) {
        float* rec = outp + ((((size_t)b * NKV + kv) * NCHUNK + chunk) * NREP + w) * RECS;
        rec[128] = m_run; rec[129] = l_run;
    }
}

// ---------------------------------------------------------------------------
// Combine chunk partials -> attn_out_t[d_model][b] (TRANSPOSED for gemv2's
// scalar-x path). grid (32 h, 16 b), 128 threads.
// ---------------------------------------------------------------------------
__global__ __launch_bounds__(128) void attn_combine(
    const float* __restrict__ part, float* __restrict__ attn_out_t)
{
    const int hq = blockIdx.x;
    const int b = blockIdx.y;
    const int kv = hq >> 2, r = hq & 3;
    const int d = threadIdx.x;
    float m_c[NCHUNK], l_c[NCHUNK];
    float M = -1e30f;
#pragma unroll
    for (int c = 0; c < NCHUNK; ++c) {
        const float* rec = part + ((((size_t)b * NKV + kv) * NCHUNK + c) * NREP + r) * RECS;
        m_c[c] = rec[128]; l_c[c] = rec[129];
        M = fmaxf(M, m_c[c]);
    }
    float num = 0.f, den = 0.f;
#pragma unroll
    for (int c = 0; c < NCHUNK; ++c) {
        const float* rec = part + ((((size_t)b * NKV + kv) * NCHUNK + c) * NREP + r) * RECS;
        float wgt = __expf(m_c[c] - M);
        num = fmaf(wgt, rec[d], num);
        den = fmaf(wgt, l_c[c], den);
    }
    attn_out_t[(size_t)(hq * DH + d) * BATCH + b] = num / den;
}

// ---------------------------------------------------------------------------
// Final reduce of output-projection partials -> d_out (fp32)
// ---------------------------------------------------------------------------
__global__ __launch_bounds__(256) void reduce_out(
    const float* __restrict__ part, float* __restrict__ out)
{
    int g = blockIdx.x * 256 + threadIdx.x;   // 0..65535
    int b = g >> 12, o = g & 4095;
    float s = 0.f;
#pragma unroll
    for (int ch = 0; ch < NDCH; ++ch)
        s += part[((size_t)ch * BATCH + b) * DMODEL + o];
    out[g] = s;
}

extern "C" void kernel_launch(void* const* d_in, const int* in_sizes, int n_in,
                              void* d_out, int out_size, void* d_ws, size_t ws_size,
                              hipStream_t stream) {
    const float* x       = (const float*)d_in[0];
    const float* cache_k = (const float*)d_in[1];
    // d_in[2] = cache_v: UNUSED (reference's PV einsum uses keys)
    const float* wq      = (const float*)d_in[3];
    const float* wk      = (const float*)d_in[4];
    // d_in[5] = wv: UNUSED
    const float* wo      = (const float*)d_in[6];
    const float* fcos    = (const float*)d_in[7];
    const float* fsin    = (const float*)d_in[8];
    const int*   sp      = (const int*)d_in[9];
    float* out = (float*)d_out;
    float* ws  = (float*)d_ws;

    // ws layout (floats); part_qk reused for part_out (disjoint lifetime)
    float* part_qk    = ws;                         // 32*16*5120 = 2,621,440
    float* xqk        = part_qk + 2621440;          // 16*5120    =    81,920
    float* xt         = xqk + 81920;                // 4096*16    =    65,536
    float* attn_part  = xt + 65536;                 // 16*8*8*4*132 = 540,672
    float* attn_out_t = attn_part + 540672;         // 4096*16    =    65,536
    float* part_out   = part_qk;                    // 32*16*4096 = 2,097,152 (reuse)

    // 1) transpose x for scalar-load gemv
    transpose_x<<<256, 256, 0, stream>>>(x, xt);
    // 2) x @ [wq | wk] partials
    gemv_part<<<dim3(QKCOLS / 256, NDCH), 256, 0, stream>>>(xt, wq, 4096, wk, 1024, part_qk);
    // 3) reduce + RoPE
    rope_reduce<<<160, 256, 0, stream>>>(part_qk, fcos, fsin, xqk);
    // 4) flash-decode attention partials (single pass over cache_k, V==K)
    attn_part_kernel<<<dim3(NCHUNK, NKV, BATCH), 256, 0, stream>>>(cache_k, xqk, sp, attn_part);
    // 5) combine chunks (writes transposed activation)
    attn_combine<<<dim3(NH, BATCH), 128, 0, stream>>>(attn_part, attn_out_t);
    // 6) attn_out @ wo partials
    gemv_part<<<dim3(DMODEL / 256, NDCH), 256, 0, stream>>>(attn_out_t, wo, 4096, nullptr, 0, part_out);
    // 7) final reduce -> d_out
    reduce_out<<<256, 256, 0, stream>>>(part_out, out);
}